// Round 6
// baseline (618.484 us; speedup 1.0000x reference)
//
#include <hip/hip_runtime.h>
#include <math.h>

#define BN    8
#define NN    1024
#define ADIM  8
#define STEPS 5
#define K2    2048                 // N*E
#define ROWS  (BN*NN)              // 8192
#define PART  ((size_t)ROWS*64)    // 524288 floats per partial segment

typedef __attribute__((ext_vector_type(8))) short bf16x8;
typedef __attribute__((ext_vector_type(4))) float f32x4;

__device__ __forceinline__ unsigned short f2bf(float f) {
    unsigned int u = __float_as_uint(f);
    u += 0x7FFF + ((u >> 16) & 1);          // round-to-nearest-even
    return (unsigned short)(u >> 16);
}

// ---------------- one-time: adjacency fp32 -> bf16 ----------------
__global__ __launch_bounds__(256) void conv_adj(
    const float* __restrict__ in, unsigned short* __restrict__ out)
{
    int tid = blockIdx.x * 256 + threadIdx.x;     // 0..2097151
    #pragma unroll
    for (int i = 0; i < 4; ++i) {
        size_t idx = (size_t)tid + (size_t)i * 2097152;
        float4 v = ((const float4*)in)[idx];
        ushort4 o;
        o.x = f2bf(v.x); o.y = f2bf(v.y); o.z = f2bf(v.z); o.w = f2bf(v.w);
        ((ushort4*)out)[idx] = o;
    }
}

// ---------------- init: h_ws = initial_state; edge0 = f(initial_state) ----------
__global__ __launch_bounds__(256) void init_kernel(
    const float* __restrict__ init_state,
    const float* __restrict__ We, const float* __restrict__ be,
    float* __restrict__ h_ws, unsigned short* __restrict__ edge_t)
{
    __shared__ float h_lds[4][65];
    int t = threadIdx.x;
    int r = t >> 6, hp = t & 63;
    int row = blockIdx.x * 4 + r;
    float hv = init_state[(size_t)row * 64 + hp];
    h_ws[(size_t)row * 64 + hp] = hv;
    h_lds[r][hp] = hv;
    __syncthreads();
    int b = row >> 10, n = row & 1023;
    #pragma unroll
    for (int e = 0; e < 2; ++e) {
        float acc = be[hp * 2 + e];
        #pragma unroll 8
        for (int c = 0; c < 64; ++c)
            acc += h_lds[r][c] * We[c * 128 + hp * 2 + e];
        edge_t[((size_t)b * 64 + hp) * K2 + e * NN + n] = f2bf(acc);
    }
}

// ---------------- big GEMM: 1024 blocks = rt(512) x khB(2); 4 blocks/CU ----------
// wave w: dir = w>>1, khW = w&1 -> each wave K=512 for its (dir, K-quarter).
// a_part seg = dir*2 + khB (4 segs); gate sums pairs.
__global__ __launch_bounds__(256, 4) void big_gemm(
    const unsigned short* __restrict__ adjb,     // [row][4096] bf16
    const unsigned short* __restrict__ edge_t,   // [b][64][2048] bf16
    float* __restrict__ a_part)
{
    __shared__ float red[4 * 16 * 68];           // 17408 B

    int bid = blockIdx.x, t = threadIdx.x;
    int rt  = bid >> 1;
    int khB = bid & 1;
    int b   = rt >> 6;                           // 64 rowtiles per batch

    int w = t >> 6, lane = t & 63, l15 = lane & 15, q = lane >> 4;
    int dir = w >> 1, khW = w & 1;

    const unsigned short* Ap = adjb + ((size_t)(rt * 16 + l15)) * 4096
                             + dir * K2 + khB * 1024 + khW * 512 + q * 8;
    const unsigned short* Bp = edge_t + (size_t)b * 64 * K2
                             + khB * 1024 + khW * 512 + q * 8;

    f32x4 acc[4];
    #pragma unroll
    for (int ct = 0; ct < 4; ++ct) acc[ct] = (f32x4){0.f, 0.f, 0.f, 0.f};

    #pragma unroll
    for (int ko = 0; ko < 2; ++ko) {
        // hoist 8 independent A-fragment loads (8 KB/wave in flight)
        bf16x8 af[8];
        #pragma unroll
        for (int ks = 0; ks < 8; ++ks)
            af[ks] = *(const bf16x8*)(Ap + (ko * 8 + ks) * 32);
        #pragma unroll
        for (int ks = 0; ks < 8; ++ks) {
            #pragma unroll
            for (int ct = 0; ct < 4; ++ct) {
                bf16x8 bfr = *(const bf16x8*)(Bp + (size_t)(ct * 16 + l15) * K2
                                              + (ko * 8 + ks) * 32);
                acc[ct] = __builtin_amdgcn_mfma_f32_16x16x32_bf16(af[ks], bfr, acc[ct], 0, 0, 0);
            }
        }
    }

    // partials -> LDS. C/D layout: col = lane&15, row = (lane>>4)*4 + reg
    {
        float* rw = red + w * (16 * 68);
        #pragma unroll
        for (int ct = 0; ct < 4; ++ct)
            #pragma unroll
            for (int i = 0; i < 4; ++i)
                rw[(q * 4 + i) * 68 + ct * 16 + l15] = acc[ct][i];
    }
    __syncthreads();

    // reduce khW pairs; write a_in (segs 0/1 by khB) and a_out (segs 2/3)
    int rloc = t >> 4, jq = t & 15;
    size_t off = ((size_t)(rt * 16 + rloc)) * 64 + jq * 4;
    float4 vin, vou;
    float* r0 = red + 0 * 1088 + rloc * 68 + jq * 4;
    float* r1 = red + 1 * 1088 + rloc * 68 + jq * 4;
    float* r2 = red + 2 * 1088 + rloc * 68 + jq * 4;
    float* r3 = red + 3 * 1088 + rloc * 68 + jq * 4;
    vin.x = r0[0] + r1[0]; vin.y = r0[1] + r1[1];
    vin.z = r0[2] + r1[2]; vin.w = r0[3] + r1[3];
    vou.x = r2[0] + r3[0]; vou.y = r2[1] + r3[1];
    vou.z = r2[2] + r3[2]; vou.w = r2[3] + r3[3];
    *(float4*)(a_part + (size_t)(0 * 2 + khB) * PART + off) = vin;
    *(float4*)(a_part + (size_t)(1 * 2 + khB) * PART + off) = vou;
}

// ---------------- gate + state update + next edge; 512 blocks, 16 rows ----------
__global__ __launch_bounds__(256, 2) void gate_kernel(
    const float* __restrict__ a_part,
    const float* __restrict__ Wg, const float* __restrict__ bg,
    const float* __restrict__ We, const float* __restrict__ be,
    float* __restrict__ h_ws, unsigned short* __restrict__ edge_t,
    int compute_edge)
{
    __shared__ float smem[15376];        // 61.5 KB
    float* Wg_l = smem;                  // 12288 floats
    float* a_l  = smem + 12288;          // 16*193
    int t = threadIdx.x, bid = blockIdx.x;
    #pragma unroll
    for (int l = 0; l < 12; ++l) {
        int idx = t + l * 256;
        *(float4*)&Wg_l[idx * 4] = *(const float4*)&Wg[idx * 4];
    }
    int rloc = t >> 4, jq = t & 15;
    int row = bid * 16 + rloc;
    size_t off = (size_t)row * 64 + jq * 4;

    float4 p0 = *(const float4*)(a_part + 0 * PART + off);
    float4 p1 = *(const float4*)(a_part + 1 * PART + off);
    float4 p2 = *(const float4*)(a_part + 2 * PART + off);
    float4 p3 = *(const float4*)(a_part + 3 * PART + off);
    float4 ain = make_float4(p0.x + p1.x, p0.y + p1.y, p0.z + p1.z, p0.w + p1.w);
    float4 aou = make_float4(p2.x + p3.x, p2.y + p3.y, p2.z + p3.z, p2.w + p3.w);
    float4 hold = *(const float4*)(h_ws + off);

    a_l[rloc * 193 + jq * 4 + 0] = ain.x; a_l[rloc * 193 + jq * 4 + 1] = ain.y;
    a_l[rloc * 193 + jq * 4 + 2] = ain.z; a_l[rloc * 193 + jq * 4 + 3] = ain.w;
    a_l[rloc * 193 + 64 + jq * 4 + 0] = aou.x; a_l[rloc * 193 + 64 + jq * 4 + 1] = aou.y;
    a_l[rloc * 193 + 64 + jq * 4 + 2] = aou.z; a_l[rloc * 193 + 64 + jq * 4 + 3] = aou.w;
    a_l[rloc * 193 + 128 + jq * 4 + 0] = hold.x; a_l[rloc * 193 + 128 + jq * 4 + 1] = hold.y;
    a_l[rloc * 193 + 128 + jq * 4 + 2] = hold.z; a_l[rloc * 193 + 128 + jq * 4 + 3] = hold.w;
    __syncthreads();

    float acc4[4] = {0.f, 0.f, 0.f, 0.f};
    #pragma unroll 8
    for (int k = 0; k < 128; ++k) {
        float av = a_l[rloc * 193 + k];
        float4 wg = *(const float4*)&Wg_l[k * 64 + jq * 4];
        acc4[0] += av * wg.x; acc4[1] += av * wg.y;
        acc4[2] += av * wg.z; acc4[3] += av * wg.w;
    }
    float zp[4] = {acc4[0], acc4[1], acc4[2], acc4[3]};
    #pragma unroll 8
    for (int k = 0; k < 64; ++k) {
        float hv = a_l[rloc * 193 + 128 + k];
        float4 wg = *(const float4*)&Wg_l[(128 + k) * 64 + jq * 4];
        zp[0] += hv * wg.x; zp[1] += hv * wg.y;
        zp[2] += hv * wg.z; zp[3] += hv * wg.w;
    }
    float4 bgv = *(const float4*)(bg + jq * 4);
    float hv4[4] = {hold.x, hold.y, hold.z, hold.w};
    float bg4[4] = {bgv.x, bgv.y, bgv.z, bgv.w};
    float z[4], zh[4];
    #pragma unroll
    for (int i = 0; i < 4; ++i) {
        z[i]  = 1.f / (1.f + __expf(-(zp[i] + bg4[i])));
        zh[i] = z[i] * hv4[i];
    }
    int gbase = (t & 63) & 48;
    #pragma unroll
    for (int k = 0; k < 64; ++k) {
        float zhk = __shfl(zh[k & 3], gbase | (k >> 2), 64);
        float4 wg = *(const float4*)&Wg_l[(128 + k) * 64 + jq * 4];
        acc4[0] += zhk * wg.x; acc4[1] += zhk * wg.y;
        acc4[2] += zhk * wg.z; acc4[3] += zhk * wg.w;
    }
    float hn[4];
    #pragma unroll
    for (int i = 0; i < 4; ++i) {
        float ht = tanhf(acc4[i] + bg4[i]);
        hn[i] = (1.f - z[i]) * hv4[i] + z[i] * ht;
    }
    *(float4*)(h_ws + off) = make_float4(hn[0], hn[1], hn[2], hn[3]);

    if (compute_edge) {
        __syncthreads();             // all Wg_l / a_l reads done
        float* We_l = smem;          // 8192 floats
        float* h_e  = smem + 12288;  // [16][65] (beyond We_l)
        #pragma unroll
        for (int l = 0; l < 8; ++l) {
            int idx = t + l * 256;
            *(float4*)&We_l[idx * 4] = *(const float4*)&We[idx * 4];
        }
        h_e[rloc * 65 + jq * 4 + 0] = hn[0]; h_e[rloc * 65 + jq * 4 + 1] = hn[1];
        h_e[rloc * 65 + jq * 4 + 2] = hn[2]; h_e[rloc * 65 + jq * 4 + 3] = hn[3];
        __syncthreads();
        float eacc[8];
        #pragma unroll
        for (int m = 0; m < 8; ++m) eacc[m] = be[jq * 8 + m];
        #pragma unroll 4
        for (int c = 0; c < 64; ++c) {
            float hv = h_e[rloc * 65 + c];
            float4 w0 = *(const float4*)&We_l[c * 128 + jq * 8];
            float4 w1 = *(const float4*)&We_l[c * 128 + jq * 8 + 4];
            eacc[0] += hv * w0.x; eacc[1] += hv * w0.y; eacc[2] += hv * w0.z; eacc[3] += hv * w0.w;
            eacc[4] += hv * w1.x; eacc[5] += hv * w1.y; eacc[6] += hv * w1.z; eacc[7] += hv * w1.w;
        }
        int bb = row >> 10, n = row & 1023;
        #pragma unroll
        for (int m = 0; m < 8; ++m) {
            int o = jq * 8 + m;
            int hp = o >> 1, e = o & 1;
            edge_t[((size_t)bb * 64 + hp) * K2 + e * NN + n] = f2bf(eacc[m]);
        }
    }
}

// ---------------- output head ----------
__global__ __launch_bounds__(256) void head_kernel(
    const float* __restrict__ h_ws, const float* __restrict__ ann,
    const float* __restrict__ Wh, const float* __restrict__ bh,
    const float* __restrict__ Wo, const float* __restrict__ bo,
    float* __restrict__ out)
{
    __shared__ float Wh_l[72 * 64];
    __shared__ float ha[4][73];
    int t = threadIdx.x;
    #pragma unroll
    for (int l = 0; l < 18; ++l) {
        int idx = t + l * 256;
        Wh_l[idx] = Wh[idx];
    }
    int r = t >> 6, hp = t & 63;
    int row = blockIdx.x * 4 + r;
    ha[r][hp] = h_ws[(size_t)row * 64 + hp];
    if (hp < ADIM) ha[r][64 + hp] = ann[(size_t)row * ADIM + hp];
    __syncthreads();

    float acc = bh[hp];
    #pragma unroll 8
    for (int k = 0; k < 72; ++k)
        acc += ha[r][k] * Wh_l[k * 64 + hp];
    float v = tanhf(acc) * Wo[hp];
    #pragma unroll
    for (int o = 32; o; o >>= 1) v += __shfl_down(v, o, 64);
    if (hp == 0) out[row] = v + bo[0];
}

extern "C" void kernel_launch(void* const* d_in, const int* in_sizes, int n_in,
                              void* d_out, int out_size, void* d_ws, size_t ws_size,
                              hipStream_t stream) {
    const float* init_state = (const float*)d_in[0];
    const float* ann = (const float*)d_in[1];
    const float* adj = (const float*)d_in[2];
    const float* We  = (const float*)d_in[3];
    const float* be  = (const float*)d_in[4];
    const float* Wg  = (const float*)d_in[5];
    const float* bg  = (const float*)d_in[6];
    const float* Wh  = (const float*)d_in[7];
    const float* bh  = (const float*)d_in[8];
    const float* Wo  = (const float*)d_in[9];
    const float* bo  = (const float*)d_in[10];
    float* out = (float*)d_out;

    // ws: adj_bf 64 MB | edge_t 2 MB | h_ws 2 MB | a_part 8 MB (4 segs)
    char* wsb = (char*)d_ws;
    unsigned short* adj_bf = (unsigned short*)wsb;
    unsigned short* edge_t = (unsigned short*)(wsb + 67108864);
    float* h_ws   = (float*)(wsb + 67108864 + 2097152);
    float* a_part = (float*)(wsb + 67108864 + 2097152 + 2097152);

    conv_adj<<<dim3(8192), dim3(256), 0, stream>>>(adj, adj_bf);
    init_kernel<<<dim3(ROWS / 4), dim3(256), 0, stream>>>(init_state, We, be, h_ws, edge_t);
    for (int s = 0; s < STEPS; ++s) {
        big_gemm<<<dim3(1024), dim3(256), 0, stream>>>(adj_bf, edge_t, a_part);
        gate_kernel<<<dim3(ROWS / 16), dim3(256), 0, stream>>>(
            a_part, Wg, bg, We, be, h_ws, edge_t, (s < STEPS - 1) ? 1 : 0);
    }
    head_kernel<<<dim3(ROWS / 4), dim3(256), 0, stream>>>(h_ws, ann, Wh, bh, Wo, bo, out);
}